// Round 11
// baseline (140.008 us; speedup 1.0000x reference)
//
#include <hip/hip_runtime.h>

// Levenshtein edit distance, ref (512,B) x hyp (512,B), B=1024, unit costs.
// TWO waves per problem (128-thread block) -> 2048 waves = 2 waves/SIMD.
// Wave w owns cells [256w, 256w+256), 4 cells/lane parity-packed
// (regs {4l+p, 4l+p+2}), VOP3P via inline asm, DPP WAVE_SHR1 boundaries.
// r9's verified algebra (absmax=0) with the r9 overheads fixed:
//  - 24-step chunks (43 + 15-step epilogue): barrier + seam-read exposure
//    amortized 2x vs r9; co-resident waves are from DIFFERENT blocks ->
//    they fill each other's dependency AND barrier stalls.
//  - tokens pre-shifted <<16 in LDS (r10), prefetched one chunk ahead (r8).
//  - seam ring 2x24 dwords: wave0 lane63 stores 6xb128 per chunk; wave1
//    reads 6xb128 at chunk top (one amortized exposure per 24 steps).
//
// Biased relative domain (r7-r10-verified exact): w = v - d + 1024.
//   AN = min(a1s, A1, a2s + nq - 2), nq = min_u16(ref^hyp, 1).
// i=0 boundary: BIASHI via DPP old (wave0). Seam cell 255->256: banked
// lane-63 dword (hi half = cell 255) as wave1's DPP old. j=0: FAKE init.

#define BATCH 1024
#define FAKE2  0x3FFF3FFFu  // packed fake-infinity (decays <=2/step, stays >1024)
#define SENT2  0x03FF03FFu  // packed sentinel tokens (real tokens < 1000)
#define SENTHI 0x03FF0000u  // pre-shifted sentinel token dword
#define BIASHI 0x04000000u  // 1024 in hi half: i=0 boundary via DPP old
#define ONE2   0x00010001u
#define NEG22  0xFFFEFFFEu

// lane i <- lane i-1; lane 0 <- old (gfx9 DPP WAVE_SHR1, HW-verified r3-r10).
__device__ __forceinline__ unsigned dpp_shr1(unsigned old, unsigned src) {
  return (unsigned)__builtin_amdgcn_update_dpp((int)old, (int)src, 0x138, 0xF, 0xF, false);
}
__device__ __forceinline__ unsigned algn(unsigned hi, unsigned lo) {
  return __builtin_amdgcn_alignbit(hi, lo, 16);  // {lo: lo.hi, hi: hi.lo}
}
__device__ __forceinline__ unsigned pkmin(unsigned a, unsigned b) {
  unsigned d; asm("v_pk_min_u16 %0, %1, %2" : "=v"(d) : "v"(a), "v"(b)); return d;
}
__device__ __forceinline__ unsigned pkadd(unsigned a, unsigned b) {
  unsigned d; asm("v_pk_add_u16 %0, %1, %2" : "=v"(d) : "v"(a), "v"(b)); return d;
}

// One step (r9-verified). QP0/QP1 swap each call; OLDV = DPP old dword
// (BIASHI for wave0, seam entry for wave1); TOKD = pre-shifted token.
#define STEP(A2, A1, AN, QP0, QP1, OLDV, TOKD)                       \
  {                                                                  \
    unsigned dA1 = dpp_shr1((OLDV), A1[1]);                          \
    unsigned a1s0 = algn(A1[1], dA1);                                \
    unsigned dHT = dpp_shr1((TOKD), QP1);                            \
    unsigned hn = algn(QP1, dHT);                                    \
    unsigned nq0 = pkmin(rt0 ^ hn, one2);                            \
    unsigned c0  = pkadd(s0c, pkadd(nq0, neg2));                     \
    AN[0] = pkmin(pkmin(a1s0, A1[0]), c0);                           \
    unsigned nq1 = pkmin(rt1 ^ QP0, one2);                           \
    unsigned c1  = pkadd(A2[0], pkadd(nq1, neg2));                   \
    AN[1] = pkmin(pkmin(A1[0], A1[1]), c1);                          \
    s0c = a1s0;                                                      \
    QP1 = hn;                                                        \
  }

__global__ void __launch_bounds__(128)
edit_distance_kernel(const int* __restrict__ ref,
                     const int* __restrict__ hyp,
                     float* __restrict__ out) {
  const int b = blockIdx.x;
  const int tid = threadIdx.x;
  const int lane = tid & 63;
  const int wave = tid >> 6;           // 0: cells 0..255, 1: cells 256..511

  // Pre-shifted padded tokens: hs[288+i] = hyp0[i]<<16. Low pad = sentinel
  // (pre-frontier), high pad [800,1344) = last token (clamp; junk j>512
  // cells only — never feed real cells, r9-verified).
  __shared__ __align__(16) unsigned hs[1344];
  __shared__ __align__(16) unsigned ring[2][24];  // seam: chunk n -> ring[n&1]

  for (int i = tid; i < 288; i += 128) hs[i] = SENTHI;
  for (int i = tid; i < 512; i += 128)
    hs[288 + i] = ((unsigned)hyp[i * BATCH + b]) << 16;
  {
    unsigned last = ((unsigned)hyp[511 * BATCH + b]) << 16;
    for (int i = 800 + tid; i < 1344; i += 128) hs[i] = last;
  }
  if (tid < 48) ((unsigned*)ring)[tid] = FAKE2;

  // Parity-packed ref tokens for local cells 4l+p (global C+4l+p).
  const int C = wave << 8;
  unsigned rt0, rt1;
  {
    unsigned e0 = (unsigned)ref[(C + 4 * lane + 0) * BATCH + b];
    unsigned e1 = (unsigned)ref[(C + 4 * lane + 1) * BATCH + b];
    unsigned e2 = (unsigned)ref[(C + 4 * lane + 2) * BATCH + b];
    unsigned e3 = (unsigned)ref[(C + 4 * lane + 3) * BATCH + b];
    rt0 = e0 | (e2 << 16);
    rt1 = e1 | (e3 << 16);
  }
  __syncthreads();  // hs + ring visible

  const unsigned one2 = ONE2, neg2 = NEG22;
  unsigned A[2], Bv[2], Cv[2];
  A[0] = A[1] = Bv[0] = Bv[1] = FAKE2;
  unsigned q0 = SENT2, q1 = SENT2;
  unsigned s0c = FAKE2;     // carried shifted-A2 seam (in-macro rename)
  unsigned scarry = FAKE2;  // wave1: previous chunk's entry-23 seam
  if (wave == 0 && lane == 0) { Bv[0] = 0x3FFF0400u; s0c = 0x3FFF0400u; }

  // Token base: wave0 injects hs[288 + d - 2] (d = 2+24n+j);
  // wave1 injects hs[e + 30] (e = 24n - 22 + j) -> base 8 + 24n.
  const int tb0 = wave ? 8 : 288;
  uint4 ta, tb, tc, td, te, tf;
  {
    const uint4* tp = (const uint4*)&hs[tb0];
    ta = tp[0]; tb = tp[1]; tc = tp[2]; td = tp[3]; te = tp[4]; tf = tp[5];
  }

  // 43 chunks x 24 steps. Wave0: d = 2+24n+j. Wave1 lags 24: e = 24n-22+j.
  for (int n = 0; n < 43; ++n) {
    uint4 na, nb, nc, nd, ne, nf;
    {
      const uint4* tp = (const uint4*)&hs[tb0 + 24 * (n + 1)];
      na = tp[0]; nb = tp[1]; nc = tp[2]; nd = tp[3]; ne = tp[4]; nf = tp[5];
    }
    if (wave == 0) {
      unsigned sn0, sn1, sn2, sn3, sn4, sn5, sn6, sn7, sn8, sn9, sn10, sn11,
               sn12, sn13, sn14, sn15, sn16, sn17, sn18, sn19, sn20, sn21,
               sn22, sn23;
      STEP(A, Bv, Cv, q0, q1, BIASHI, ta.x);  sn0  = Cv[1];
      STEP(Bv, Cv, A, q1, q0, BIASHI, ta.y);  sn1  = A[1];
      STEP(Cv, A, Bv, q0, q1, BIASHI, ta.z);  sn2  = Bv[1];
      STEP(A, Bv, Cv, q1, q0, BIASHI, ta.w);  sn3  = Cv[1];
      STEP(Bv, Cv, A, q0, q1, BIASHI, tb.x);  sn4  = A[1];
      STEP(Cv, A, Bv, q1, q0, BIASHI, tb.y);  sn5  = Bv[1];
      STEP(A, Bv, Cv, q0, q1, BIASHI, tb.z);  sn6  = Cv[1];
      STEP(Bv, Cv, A, q1, q0, BIASHI, tb.w);  sn7  = A[1];
      STEP(Cv, A, Bv, q0, q1, BIASHI, tc.x);  sn8  = Bv[1];
      STEP(A, Bv, Cv, q1, q0, BIASHI, tc.y);  sn9  = Cv[1];
      STEP(Bv, Cv, A, q0, q1, BIASHI, tc.z);  sn10 = A[1];
      STEP(Cv, A, Bv, q1, q0, BIASHI, tc.w);  sn11 = Bv[1];
      STEP(A, Bv, Cv, q0, q1, BIASHI, td.x);  sn12 = Cv[1];
      STEP(Bv, Cv, A, q1, q0, BIASHI, td.y);  sn13 = A[1];
      STEP(Cv, A, Bv, q0, q1, BIASHI, td.z);  sn14 = Bv[1];
      STEP(A, Bv, Cv, q1, q0, BIASHI, td.w);  sn15 = Cv[1];
      STEP(Bv, Cv, A, q0, q1, BIASHI, te.x);  sn16 = A[1];
      STEP(Cv, A, Bv, q1, q0, BIASHI, te.y);  sn17 = Bv[1];
      STEP(A, Bv, Cv, q0, q1, BIASHI, te.z);  sn18 = Cv[1];
      STEP(Bv, Cv, A, q1, q0, BIASHI, te.w);  sn19 = A[1];
      STEP(Cv, A, Bv, q0, q1, BIASHI, tf.x);  sn20 = Bv[1];
      STEP(A, Bv, Cv, q1, q0, BIASHI, tf.y);  sn21 = Cv[1];
      STEP(Bv, Cv, A, q0, q1, BIASHI, tf.z);  sn22 = A[1];
      STEP(Cv, A, Bv, q1, q0, BIASHI, tf.w);  sn23 = Bv[1];
      if (lane == 63) {   // bank BW(2+24n .. 25+24n) into ring[n&1]
        uint4* dst = (uint4*)&ring[n & 1][0];
        dst[0] = make_uint4(sn0, sn1, sn2, sn3);
        dst[1] = make_uint4(sn4, sn5, sn6, sn7);
        dst[2] = make_uint4(sn8, sn9, sn10, sn11);
        dst[3] = make_uint4(sn12, sn13, sn14, sn15);
        dst[4] = make_uint4(sn16, sn17, sn18, sn19);
        dst[5] = make_uint4(sn20, sn21, sn22, sn23);
      }
    } else {
      // Seams: chunk n-1's banked BW(2+24(n-1)+j) from ring[(n+1)&1].
      // Step j uses entry j-1 (A1-seam BW(e_j - 1)); j=0 uses scarry.
      const uint4* src = (const uint4*)&ring[(n + 1) & 1][0];
      uint4 sa = src[0], sb = src[1], sc = src[2];
      uint4 sd = src[3], se = src[4], sf = src[5];
      STEP(A, Bv, Cv, q0, q1, scarry, ta.x);
      STEP(Bv, Cv, A, q1, q0, sa.x,   ta.y);
      STEP(Cv, A, Bv, q0, q1, sa.y,   ta.z);
      STEP(A, Bv, Cv, q1, q0, sa.z,   ta.w);
      STEP(Bv, Cv, A, q0, q1, sa.w,   tb.x);
      STEP(Cv, A, Bv, q1, q0, sb.x,   tb.y);
      STEP(A, Bv, Cv, q0, q1, sb.y,   tb.z);
      STEP(Bv, Cv, A, q1, q0, sb.z,   tb.w);
      STEP(Cv, A, Bv, q0, q1, sb.w,   tc.x);
      STEP(A, Bv, Cv, q1, q0, sc.x,   tc.y);
      STEP(Bv, Cv, A, q0, q1, sc.y,   tc.z);
      STEP(Cv, A, Bv, q1, q0, sc.z,   tc.w);
      STEP(A, Bv, Cv, q0, q1, sc.w,   td.x);
      STEP(Bv, Cv, A, q1, q0, sd.x,   td.y);
      STEP(Cv, A, Bv, q0, q1, sd.y,   td.z);
      STEP(A, Bv, Cv, q1, q0, sd.z,   td.w);
      STEP(Bv, Cv, A, q0, q1, sd.w,   te.x);
      STEP(Cv, A, Bv, q1, q0, se.x,   te.y);
      STEP(A, Bv, Cv, q0, q1, se.y,   te.z);
      STEP(Bv, Cv, A, q1, q0, se.z,   te.w);
      STEP(Cv, A, Bv, q0, q1, se.w,   tf.x);
      STEP(A, Bv, Cv, q1, q0, sf.x,   tf.y);
      STEP(Bv, Cv, A, q0, q1, sf.y,   tf.z);
      STEP(Cv, A, Bv, q1, q0, sf.z,   tf.w);
      scarry = sf.w;   // entry 23 = BW(24n+1), used next chunk at j=0
    }
    __syncthreads();   // publish ring[n&1]; protect ring[(n+2)&1] reuse
    ta = na; tb = nb; tc = nc; td = nd; te = ne; tf = nf;
  }

  // Wave1 epilogue: e = 1010..1024 (15 steps). Seams: scarry = BW(1009)
  // (chunk-41 entry 23, set at n=42); entries BW(1010..1023) = chunk-42
  // ring[0] entries 0..13 (visible after final barrier). Tokens: the
  // prefetched "chunk 43" regs = hs[1040..] (= hs[e+30]).  24%6==0 keeps
  // buffer/queue phases aligned; 15%3==0 -> answer lands in Bv.
  if (wave == 1) {
    const uint4* src = (const uint4*)&ring[0][0];
    uint4 sa = src[0], sb = src[1], sc = src[2], sd = src[3];
    STEP(A, Bv, Cv, q0, q1, scarry, ta.x);  // e = 1010
    STEP(Bv, Cv, A, q1, q0, sa.x,   ta.y);
    STEP(Cv, A, Bv, q0, q1, sa.y,   ta.z);
    STEP(A, Bv, Cv, q1, q0, sa.z,   ta.w);
    STEP(Bv, Cv, A, q0, q1, sa.w,   tb.x);
    STEP(Cv, A, Bv, q1, q0, sb.x,   tb.y);
    STEP(A, Bv, Cv, q0, q1, sb.y,   tb.z);
    STEP(Bv, Cv, A, q1, q0, sb.z,   tb.w);
    STEP(Cv, A, Bv, q0, q1, sb.w,   tc.x);
    STEP(A, Bv, Cv, q1, q0, sc.x,   tc.y);
    STEP(Bv, Cv, A, q0, q1, sc.y,   tc.z);
    STEP(Cv, A, Bv, q1, q0, sc.z,   tc.w);  // e = 1021
    STEP(A, Bv, Cv, q0, q1, sc.w,   td.x);  // e = 1022
    STEP(Bv, Cv, A, q1, q0, sd.x,   td.y);  // e = 1023
    STEP(Cv, A, Bv, q0, q1, sd.y,   td.z);  // e = 1024 -> Bv
    // Answer: global cell 511 = lane 63, pair 1, HIGH half; at d=1024, w=v.
    if (lane == 63) out[b] = (float)(Bv[1] >> 16);
  }
}

extern "C" void kernel_launch(void* const* d_in, const int* in_sizes, int n_in,
                              void* d_out, int out_size, void* d_ws, size_t ws_size,
                              hipStream_t stream) {
  const int* ref = (const int*)d_in[0];
  const int* hyp = (const int*)d_in[1];
  float* out = (float*)d_out;
  edit_distance_kernel<<<BATCH, 128, 0, stream>>>(ref, hyp, out);
}

// Round 12
// 131.603 us; speedup vs baseline: 1.0639x; 1.0639x over previous
//
#include <hip/hip_runtime.h>

// Levenshtein edit distance, ref (512,B) x hyp (512,B), B=1024, unit costs.
// One 64-lane wave per problem, 8 cells/lane parity-packed (reg p = cells
// {8l+p, 8l+p+4}), anti-diagonal wavefront. r8's verified algebra (absmax=0),
// now with the ENTIRE step in ONE hand-scheduled asm block:
//  - Evidence r6-r11: wall = instr x ~6.2 cyc when ops are separate asm
//    nodes (scheduler can't interleave them); r6's compiler-scheduled code
//    ran at 3.4 cyc/instr. Fix: schedule by hand inside a single block,
//    pair-chains round-robin (ILP 4), DPP write-read gaps >= 2 instrs.
//  - AN tied in-place onto A2 (diag d-2 dead once d built): 2 value buffers.
//  - nq-2 via OR (nq | 0xFFFE == nq - 2 for nq in {0,1}).
//  - tokens pre-shifted <<16 in LDS (r10), 12 prefetched per 12-step body.
//
// Biased relative domain (r7-r11-verified): w = v - d + 1024 in [0,1024].
//   AN = min(a1s, A1, a2s + nq - 2), nq = min_u16(ref^hyp, 1).
// i=0 boundary: 1024 in hi half via DPP old. j=0: FAKE init. Answer: w = v
// at d = 1024.

#define HLEN 512
#define BATCH 1024
#define FAKE2  0x3FFF3FFFu
#define SENT2  0x03FF03FFu
#define BIASHI 0x04000000u
#define ONE2   0x00010001u
#define NEG22  0xFFFEFFFEu

// One step, hand-scheduled. AB = A2 in / AN out (in-place). A1 read-only.
// Queue: Q3 = DPP src, replaced by the shifted queue; Q0-Q2 read-only;
// call sites rotate (q0,q1,q2,q3)->(q3,q0,q1,q2)->... period 4.
// TOK ("+v") doubles as scratch e2 after its single read.
#define STEP(AB, A1, Q0, Q1, Q2, Q3, TOK)                                \
  {                                                                      \
    unsigned dv, dt, x0, x1, x2, x3, e3;                                 \
    asm("v_mov_b32 %[dv], %[bias]\n\t"                                   \
        "v_mov_b32 %[dt], %[tok]\n\t"                                    \
        "v_xor_b32 %[x1], %[rt1], %[vq0]\n\t"                            \
        "v_xor_b32 %[x2], %[rt2], %[vq1]\n\t"                            \
        "v_xor_b32 %[x3], %[rt3], %[vq2]\n\t"                            \
        "v_mov_b32_dpp %[dv], %[a13] wave_shr:1 row_mask:0xf bank_mask:0xf\n\t" \
        "v_mov_b32_dpp %[dt], %[vq3] wave_shr:1 row_mask:0xf bank_mask:0xf\n\t" \
        "v_pk_min_u16 %[x1], %[x1], %[one]\n\t"                          \
        "v_pk_min_u16 %[x2], %[x2], %[one]\n\t"                          \
        "v_pk_min_u16 %[x3], %[x3], %[one]\n\t"                          \
        "v_alignbit_b32 %[vq3], %[vq3], %[dt], 16\n\t"                   \
        "v_or_b32 %[x1], %[x1], %[neg2]\n\t"                             \
        "v_or_b32 %[x2], %[x2], %[neg2]\n\t"                             \
        "v_or_b32 %[x3], %[x3], %[neg2]\n\t"                             \
        "v_xor_b32 %[x0], %[rt0], %[vq3]\n\t"                            \
        "v_pk_add_u16 %[x1], %[ab0], %[x1]\n\t"                          \
        "v_pk_add_u16 %[x2], %[ab1], %[x2]\n\t"                          \
        "v_pk_add_u16 %[x3], %[ab2], %[x3]\n\t"                          \
        "v_pk_min_u16 %[x0], %[x0], %[one]\n\t"                          \
        "v_pk_min_u16 %[dt], %[a10], %[a11]\n\t"                         \
        "v_pk_min_u16 %[tok], %[a11], %[a12]\n\t"                        \
        "v_pk_min_u16 %[e3], %[a12], %[a13]\n\t"                         \
        "v_or_b32 %[x0], %[x0], %[neg2]\n\t"                             \
        "v_pk_add_u16 %[x0], %[s0c], %[x0]\n\t"                          \
        "v_alignbit_b32 %[s0c], %[a13], %[dv], 16\n\t"                   \
        "v_pk_min_u16 %[dv], %[s0c], %[a10]\n\t"                         \
        "v_pk_min_u16 %[ab1], %[dt], %[x1]\n\t"                          \
        "v_pk_min_u16 %[ab2], %[tok], %[x2]\n\t"                         \
        "v_pk_min_u16 %[ab3], %[e3], %[x3]\n\t"                          \
        "v_pk_min_u16 %[ab0], %[dv], %[x0]"                              \
        : [ab0] "+v"(AB[0]), [ab1] "+v"(AB[1]), [ab2] "+v"(AB[2]),       \
          [ab3] "+v"(AB[3]), [vq3] "+v"(Q3), [s0c] "+v"(s0c),            \
          [tok] "+v"(TOK),                                               \
          [dv] "=&v"(dv), [dt] "=&v"(dt), [x0] "=&v"(x0),                \
          [x1] "=&v"(x1), [x2] "=&v"(x2), [x3] "=&v"(x3),                \
          [e3] "=&v"(e3)                                                 \
        : [a10] "v"(A1[0]), [a11] "v"(A1[1]), [a12] "v"(A1[2]),          \
          [a13] "v"(A1[3]), [vq0] "v"(Q0), [vq1] "v"(Q1),                \
          [vq2] "v"(Q2), [rt0] "v"(rt[0]), [rt1] "v"(rt[1]),             \
          [rt2] "v"(rt[2]), [rt3] "v"(rt[3]), [one] "v"(one2),           \
          [neg2] "v"(neg2), [bias] "v"(biasv));                          \
  }

__global__ void __launch_bounds__(64)
edit_distance_kernel(const int* __restrict__ ref,
                     const int* __restrict__ hyp,
                     float* __restrict__ out) {
  const int b = blockIdx.x;        // one wave (block of 64) per batch element
  const int lane = threadIdx.x;    // 0..63

  // Pre-shifted hyp tokens in LDS: hs[i] = hyp0[i] << 16.
  __shared__ unsigned hs[HLEN];
#pragma unroll
  for (int c = 0; c < HLEN / 64; ++c)
    hs[c * 64 + lane] = ((unsigned)hyp[(c * 64 + lane) * BATCH + b]) << 16;

  // Parity-packed static ref tokens: rt[p] = {cell 8l+p, cell 8l+p+4}.
  unsigned rt[4];
#pragma unroll
  for (int p = 0; p < 4; ++p) {
    unsigned lo = (unsigned)ref[(lane * 8 + p) * BATCH + b];
    unsigned hi = (unsigned)ref[(lane * 8 + p + 4) * BATCH + b];
    rt[p] = lo | (hi << 16);
  }
  __syncthreads();

  const unsigned one2 = ONE2, neg2 = NEG22, biasv = BIASHI;

  // TWO rotating value buffers (AN overwrites A2 in place).
  // X = diag 0 (all fake), Y = diag 1 (lane0 cell0: w=1024).
  unsigned X[4], Y[4];
  X[0] = X[1] = X[2] = X[3] = FAKE2;
  Y[0] = Y[1] = Y[2] = Y[3] = FAKE2;
  unsigned q0 = SENT2, q1 = SENT2, q2 = SENT2, q3 = SENT2;
  // Carried shifted-A2 seam = shifted diag 0 (r8-verified init).
  unsigned s0c = (lane == 0) ? 0x3FFF0400u : FAKE2;
  if (lane == 0) Y[0] = 0x3FFF0400u;

  // Token regs for current 12-step body: step d=2+12it+j injects hs[12it+j].
  unsigned t[12], tn[12];
#pragma unroll
  for (int j = 0; j < 12; ++j) t[j] = hs[j];

  // 85 iterations x 12 steps = d = 2..1021.
  for (int it = 0; it < 85; ++it) {
    const int base = 12 + it * 12;
#pragma unroll
    for (int j = 0; j < 12; ++j) tn[j] = hs[min(base + j, HLEN - 1)];
    STEP(X, Y, q0, q1, q2, q3, t[0]);   // X <- diag 2+12it
    STEP(Y, X, q3, q0, q1, q2, t[1]);
    STEP(X, Y, q2, q3, q0, q1, t[2]);
    STEP(Y, X, q1, q2, q3, q0, t[3]);
    STEP(X, Y, q0, q1, q2, q3, t[4]);
    STEP(Y, X, q3, q0, q1, q2, t[5]);
    STEP(X, Y, q2, q3, q0, q1, t[6]);
    STEP(Y, X, q1, q2, q3, q0, t[7]);
    STEP(X, Y, q0, q1, q2, q3, t[8]);
    STEP(Y, X, q3, q0, q1, q2, t[9]);
    STEP(X, Y, q2, q3, q0, q1, t[10]);
    STEP(Y, X, q1, q2, q3, q0, t[11]);  // Y <- diag 13+12it
#pragma unroll
    for (int j = 0; j < 12; ++j) t[j] = tn[j];
  }

  // Epilogue: d = 1022, 1023, 1024 (tokens clamped -> junk j>511 cells only).
  STEP(X, Y, q0, q1, q2, q3, t[0]);  // X <- 1022
  STEP(Y, X, q3, q0, q1, q2, t[1]);  // Y <- 1023
  STEP(X, Y, q2, q3, q0, q1, t[2]);  // X <- 1024

  // Answer: cell 511 = lane 63, pair 3, HIGH half; at d = 1024, w = v.
  if (lane == 63) out[b] = (float)(X[3] >> 16);
}

extern "C" void kernel_launch(void* const* d_in, const int* in_sizes, int n_in,
                              void* d_out, int out_size, void* d_ws, size_t ws_size,
                              hipStream_t stream) {
  const int* ref = (const int*)d_in[0];
  const int* hyp = (const int*)d_in[1];
  float* out = (float*)d_out;
  edit_distance_kernel<<<BATCH, 64, 0, stream>>>(ref, hyp, out);
}